// Round 3
// baseline (436.669 us; speedup 1.0000x reference)
//
#include <hip/hip_runtime.h>
#include <hip/hip_bf16.h>

typedef __bf16 bf16_t;
typedef __attribute__((ext_vector_type(8))) __bf16 bf16x8;
typedef __attribute__((ext_vector_type(4))) float f32x4;

#define S_DIM 4096
#define D_DIM 2048

__device__ __forceinline__ unsigned short f2bf(float f) {
  unsigned int u = __float_as_uint(f);
  u += 0x7fff + ((u >> 16) & 1);   // round-to-nearest-even
  return (unsigned short)(u >> 16);
}
__device__ __forceinline__ float bf2f(unsigned short h) {
  return __uint_as_float(((unsigned int)h) << 16);
}

// async global->LDS, 16B per lane. LDS dest must be wave-uniform base + lane*16.
__device__ __forceinline__ void async16(const void* g, void* l) {
  __builtin_amdgcn_global_load_lds(
      (const __attribute__((address_space(1))) void*)g,
      (__attribute__((address_space(3))) void*)l, 16, 0, 0);
}

// ---------------------------------------------------------------------------
// init: zero rowsum[4096]; block 0 also runs the dtype probe.
__global__ void k_init(const unsigned int* __restrict__ x, int* __restrict__ flag,
                       float* __restrict__ rowsum) {
  const int idx = blockIdx.x * 256 + threadIdx.x;
  if (idx < S_DIM) rowsum[idx] = 0.f;
  if (blockIdx.x == 0) {
    __shared__ int cnt;
    if (threadIdx.x == 0) cnt = 0;
    __syncthreads();
    const unsigned int e = (x[threadIdx.x] >> 7) & 0xffu;
    if (e >= 100 && e <= 140) atomicAdd(&cnt, 1);
    __syncthreads();
    if (threadIdx.x == 0) *flag = (cnt > 128) ? 1 : 0;
  }
}

// convert (or copy) input to bf16; 4 elements per thread
__global__ void k_tobf16(const void* __restrict__ src, unsigned short* __restrict__ dst,
                         int n4, const int* __restrict__ flag) {
  int i = blockIdx.x * 256 + threadIdx.x;
  if (i >= n4) return;
  if (*flag) {
    ((uint2*)dst)[i] = ((const uint2*)src)[i];
  } else {
    float4 f = ((const float4*)src)[i];
    ushort4 u;
    u.x = f2bf(f.x); u.y = f2bf(f.y); u.z = f2bf(f.z); u.w = f2bf(f.w);
    ((ushort4*)dst)[i] = u;
  }
}

// all three weight matrices in one launch; i in [0, 3*2048*2048/4)
__global__ void k_tobf16w(const void* __restrict__ s0, const void* __restrict__ s1,
                          const void* __restrict__ s2, unsigned short* __restrict__ dst,
                          const int* __restrict__ flag) {
  const int i = blockIdx.x * 256 + threadIdx.x;      // 3 * 1048576 total
  const int which = i >> 20;
  const int off = i & 0xFFFFF;
  const void* src = (which == 0) ? s0 : ((which == 1) ? s1 : s2);
  if (*flag) {
    ((uint2*)dst)[i] = ((const uint2*)src)[off];
  } else {
    float4 f = ((const float4*)src)[off];
    ushort4 u;
    u.x = f2bf(f.x); u.y = f2bf(f.y); u.z = f2bf(f.z); u.w = f2bf(f.w);
    ((ushort4*)dst)[i] = u;
  }
}

// ---------------------------------------------------------------------------
// 8-phase-lite deep-pipelined GEMM template (T2+T3+T4+T5 from the guide).
// C[.,n] = A[.,K] * B[n,K]^T, bf16 in, fp32 accum.
// BM=256, BN=128, BK=64 (two k-halves of 32). 512 thr = 8 waves (2M x 4N),
// per-wave 128x32 out -> acc[8][2] f32x4 (64 VGPR).
// LDS 96KB = 2 bufs x { A[2][256x32], B[2][128x32] } -> 1 block/CU, 2 w/SIMD.
//
// Swizzle (T2): region byte x holds logical byte swz(x) = x ^ (((x>>7)&3)<<4)
// (involution, touches only bits 4-5; source bits 7-8 untouched). For 64B rows
// this spreads 8 consecutive rows across 8 distinct 16B bank-slots -> the
// 16-consecutive-row ds_read_b128 column-slice is 2 lanes/bank = free (m136).
// global_load_lds writes LINEARLY (rule #21), so the swizzle is applied by
// pre-swizzling the per-lane GLOBAL source (kslot ^= (tid>>3)&3) and the
// ds_read address (kslot ^= (row>>1)&3); both sides same involution.
//
// Pipeline (T3+T4): phase = one k-half: { ds_read(ks) | stage one future
// half (3 x global_load_lds) | s_waitcnt vmcnt(6) | s_barrier | 16 MFMA
// (setprio-wrapped, T5) | s_barrier }. Halves are staged 3 phases before
// consumption; vmcnt(6) (= 2 phases x 3 loads in flight) never drains the
// queue in steady state. Tail: 6 -> 3 -> 0. Stage targets are always regions
// whose last reader finished a closed-barrier phase earlier (no WAR race).
// Raw s_barrier (NOT __syncthreads) so the compiler doesn't emit vmcnt(0).
template<int OUT_MODE>   // 0 = bf16 out (qkv); 2 = /rowsum, flag?bf16:f32 (av)
__device__ __forceinline__ void gemm8_body(
    const bf16_t* __restrict__ A, const bf16_t* __restrict__ B,
    void* __restrict__ C, int ldA, int ldB, int ldC,
    int bm, int bn, int NT,            // NT = K-tiles of 64 (>= 2)
    const int* __restrict__ flag, const float* __restrict__ rowsum,
    bf16_t* sm) {
  const int tid = threadIdx.x;
  const int lane = tid & 63;
  const int wave = tid >> 6;
  const int quad = lane >> 4, l16 = lane & 15;
  const int wr = wave >> 2;            // 0..1  (128-row band)
  const int wc = wave & 3;             // 0..3  (32-col band)
  const int swq = (l16 >> 1) & 3;      // read-side swizzle, lane-constant

  // staging constants: thread t covers region bytes [t*16, t*16+16) (+8KB for
  // A's second 128 rows); pre-swizzled source k-slot:
  const int sr2 = tid >> 2;                              // region row 0..127
  const int kb = (((tid & 3) ^ ((tid >> 3) & 3)) * 8);   // source k elems
  const unsigned aRow = (unsigned)bm * 256u;
  const unsigned bRow = (unsigned)bn * 128u;

  // region element offsets inside sm (49152 elems = 96KB)
  auto Aoff = [](int buf, int ks) { return buf * 24576 + ks * 8192; };
  auto Boff = [](int buf, int ks) { return buf * 24576 + 16384 + ks * 4096; };

  auto stage = [&](int buf, int ks, int T) {
    const int kcol = T * 64 + ks * 32 + kb;
    const bf16_t* ga0 = A + (size_t)(aRow + sr2) * (unsigned)ldA + kcol;
    const bf16_t* ga1 = A + (size_t)(aRow + 128 + sr2) * (unsigned)ldA + kcol;
    const bf16_t* gb  = B + (size_t)(bRow + sr2) * (unsigned)ldB + kcol;
    async16(ga0, &sm[Aoff(buf, ks) + tid * 8]);
    async16(ga1, &sm[Aoff(buf, ks) + 4096 + tid * 8]);
    async16(gb,  &sm[Boff(buf, ks) + tid * 8]);
  };

  f32x4 acc[8][2] = {};

  // prologue: tile0 both halves + tile1 k0  (9 loads/thread)
  stage(0, 0, 0);
  stage(0, 1, 0);
  stage(1, 0, 1);
  asm volatile("s_waitcnt vmcnt(6)" ::: "memory");   // tile0.k0 landed
  __builtin_amdgcn_s_barrier();

  for (int T = 0; T < NT; ++T) {
    const int buf = T & 1;
#pragma unroll
    for (int ks = 0; ks < 2; ++ks) {
      bf16x8 a[8], b[2];
      const int ab = Aoff(buf, ks), bb = Boff(buf, ks);
#pragma unroll
      for (int i = 0; i < 8; ++i)
        a[i] = *(const bf16x8*)&sm[ab + (wr * 128 + i * 16 + l16) * 32 +
                                   ((quad ^ swq) * 8)];
#pragma unroll
      for (int j = 0; j < 2; ++j)
        b[j] = *(const bf16x8*)&sm[bb + (wc * 32 + j * 16 + l16) * 32 +
                                   ((quad ^ swq) * 8)];
      if (ks == 0) {
        // stage (T+1).k1 -> other buf (its last reader was phase T-1.P2)
        if (T + 1 < NT) {
          stage(buf ^ 1, 1, T + 1);
          asm volatile("s_waitcnt vmcnt(6)" ::: "memory");
        } else {
          asm volatile("s_waitcnt vmcnt(0)" ::: "memory");
        }
      } else {
        // stage (T+2).k0 -> same buf's k0 (last read in P1 of this tile)
        if (T + 2 < NT) {
          stage(buf, 0, T + 2);
          asm volatile("s_waitcnt vmcnt(6)" ::: "memory");
        } else if (T + 1 < NT) {
          asm volatile("s_waitcnt vmcnt(3)" ::: "memory");
        }
      }
      __builtin_amdgcn_s_barrier();
      __builtin_amdgcn_s_setprio(1);
#pragma unroll
      for (int i = 0; i < 8; ++i)
#pragma unroll
        for (int j = 0; j < 2; ++j)
          acc[i][j] =
              __builtin_amdgcn_mfma_f32_16x16x32_bf16(a[i], b[j], acc[i][j], 0, 0, 0);
      __builtin_amdgcn_s_setprio(0);
      __builtin_amdgcn_s_barrier();
    }
  }

  if (OUT_MODE == 0) {
#pragma unroll
    for (int i = 0; i < 8; ++i) {
      const int gr0 = bm * 256 + wr * 128 + i * 16 + quad * 4;
#pragma unroll
      for (int j = 0; j < 2; ++j) {
        const int gc = bn * 128 + wc * 32 + j * 16 + l16;
#pragma unroll
        for (int r = 0; r < 4; ++r)
          ((unsigned short*)C)[(size_t)(gr0 + r) * ldC + gc] = f2bf(acc[i][j][r]);
      }
    }
  } else {
    const bool obf = (*flag != 0);
#pragma unroll
    for (int i = 0; i < 8; ++i) {
      const int gr0 = bm * 256 + wr * 128 + i * 16 + quad * 4;
      float inv[4];
#pragma unroll
      for (int r = 0; r < 4; ++r) inv[r] = 1.0f / rowsum[gr0 + r];
#pragma unroll
      for (int j = 0; j < 2; ++j) {
        const int gc = bn * 128 + wc * 32 + j * 16 + l16;
#pragma unroll
        for (int r = 0; r < 4; ++r) {
          const float v = acc[i][j][r] * inv[r];
          const size_t idx = (size_t)(gr0 + r) * ldC + gc;
          if (obf) ((unsigned short*)C)[idx] = f2bf(v);
          else     ((float*)C)[idx] = v;
        }
      }
    }
  }
}

__global__ __launch_bounds__(512, 2)
void k_gemm_qkv8(const bf16_t* __restrict__ A, const bf16_t* __restrict__ B,
                 void* __restrict__ C, const int* __restrict__ flag) {
  __shared__ alignas(16) bf16_t sm[49152];
  gemm8_body<0>(A, B, C, D_DIM, D_DIM, 6144, blockIdx.y, blockIdx.x, 32,
                flag, nullptr, sm);
}

__global__ __launch_bounds__(512, 2)
void k_gemm_av8(const bf16_t* __restrict__ A, const bf16_t* __restrict__ B,
                void* __restrict__ C, const int* __restrict__ flag,
                const float* __restrict__ rowsum) {
  __shared__ alignas(16) bf16_t sm[49152];
  const int bmv = blockIdx.y;                 // 0..15, kEnd = (bmv+1)*256
  gemm8_body<2>(A, B, C, S_DIM, S_DIM, D_DIM, bmv, blockIdx.x, 4 * (bmv + 1),
                flag, rowsum, sm);
}

// ---------------------------------------------------------------------------
// av at BM=256 reads one super-diagonal 128-tile per 256-row band that the
// sc triangle never writes: rows [t*256, t*256+128) x cols [(2t+1)*128,
// (2t+2)*128). Zero those 16 tiles (attn aliases xb -> garbage otherwise).
__global__ void k_zerodiag(unsigned short* __restrict__ attn) {
  const int t = blockIdx.x;
  const size_t rowB = (size_t)t * 256;
  const size_t colB = (size_t)(2 * t + 1) * 128;
  const uint4 z = {0, 0, 0, 0};
  for (int c = threadIdx.x; c < 2048; c += 256) {
    const int r = c >> 4, c8 = (c & 15) * 8;
    *(uint4*)&attn[(rowB + r) * S_DIM + colB + c8] = z;
  }
}

// ---------------------------------------------------------------------------
// old m97-style 2-barrier body, kept for sc (triangle shape mismatches
// 256-row tiles; port next round). 128x128 tile, 256 thr, waves 2x2.
// OUT_MODE 3: softmax-fused scores epilogue.
template<int OUT_MODE, int CAUSAL, int TM>
__device__ __forceinline__ void gemm_body(
    const bf16_t* __restrict__ A, const bf16_t* __restrict__ B,
    void* __restrict__ C, int ldA, int ldB, int ldC, int K,
    float scale, const int* __restrict__ flag,
    const void* __restrict__ mask, float* __restrict__ rowsum) {
  constexpr int NJ = (TM == 128) ? 4 : 2;
  int bm, bn;
  if (CAUSAL == 1) {
    const int t = blockIdx.x;
    int u = (int)((sqrtf(8.0f * (float)t + 1.0f) - 1.0f) * 0.5f);
    while (((u + 1) * (u + 2)) / 2 <= t) ++u;
    while ((u * (u + 1)) / 2 > t) --u;
    bm = u;
    bn = t - (u * (u + 1)) / 2;
  } else {
    bm = blockIdx.y;
    bn = blockIdx.x;
  }
  const int rowBase = bm * TM;

  __shared__ alignas(16) bf16_t As0[TM * 32];
  __shared__ alignas(16) bf16_t As1[TM * 32];
  __shared__ alignas(16) bf16_t Bs0[128 * 32];
  __shared__ alignas(16) bf16_t Bs1[128 * 32];

  const int tid = threadIdx.x;
  const int lane = tid & 63, wave = tid >> 6;
  const int quad = lane >> 4, l16 = lane & 15;
  const int wm = (wave >> 1) * 64;
  const int wn = (wave & 1) * 64;
  const int sr = tid >> 2;
  const int sc = (tid & 3) * 8;

  const int kEnd = K;

  f32x4 acc[4][NJ] = {};

  const unsigned aOff = (unsigned)(rowBase + sr) * (unsigned)ldA + sc;
  const unsigned bOff = (unsigned)(bn * 128 + sr) * (unsigned)ldB + sc;
  const unsigned aOff2 = aOff + 64u * (unsigned)ldA;
  const unsigned bOff2 = bOff + 64u * (unsigned)ldB;
  const unsigned lOff = sr * 32 + sc;

  for (int k0 = 0; k0 < kEnd; k0 += 64) {
    async16(A + (aOff + k0), &As0[lOff]);
    async16(A + (aOff + k0 + 32), &As1[lOff]);
    async16(A + (aOff2 + k0), &As0[lOff + 64 * 32]);
    async16(A + (aOff2 + k0 + 32), &As1[lOff + 64 * 32]);
    async16(B + (bOff + k0), &Bs0[lOff]);
    async16(B + (bOff2 + k0), &Bs0[lOff + 64 * 32]);
    async16(B + (bOff + k0 + 32), &Bs1[lOff]);
    async16(B + (bOff2 + k0 + 32), &Bs1[lOff + 64 * 32]);
    __syncthreads();

    bf16x8 b0[NJ], b1[NJ];
#pragma unroll
    for (int j = 0; j < NJ; ++j) {
      b0[j] = *(const bf16x8*)&Bs0[(wn + j * 16 + l16) * 32 + quad * 8];
      b1[j] = *(const bf16x8*)&Bs1[(wn + j * 16 + l16) * 32 + quad * 8];
    }
#pragma unroll
    for (int i = 0; i < 4; ++i) {
      const bf16x8 a0 = *(const bf16x8*)&As0[(wm + i * 16 + l16) * 32 + quad * 8];
      const bf16x8 a1 = *(const bf16x8*)&As1[(wm + i * 16 + l16) * 32 + quad * 8];
#pragma unroll
      for (int j = 0; j < NJ; ++j) {
        acc[i][j] = __builtin_amdgcn_mfma_f32_16x16x32_bf16(a0, b0[j], acc[i][j], 0, 0, 0);
        acc[i][j] = __builtin_amdgcn_mfma_f32_16x16x32_bf16(a1, b1[j], acc[i][j], 0, 0, 0);
      }
    }
    __syncthreads();
  }

  // scores epilogue: exp + dropout-mask + per-row sum
  const bool mbf = (*flag != 0);
  float rp[4][4];
#pragma unroll
  for (int i = 0; i < 4; ++i)
#pragma unroll
    for (int r = 0; r < 4; ++r) rp[i][r] = 0.f;
#pragma unroll
  for (int i = 0; i < 4; ++i) {
    const int gr0 = rowBase + wm + i * 16 + quad * 4;
#pragma unroll
    for (int j = 0; j < NJ; ++j) {
      const int gc = bn * 128 + wn + j * 16 + l16;
#pragma unroll
      for (int r = 0; r < 4; ++r) {
        const int grr = gr0 + r;
        float out = 0.f;
        if (gc <= grr) {
          const float e = __expf(acc[i][j][r] * scale);
          const size_t mIdx = (size_t)grr * S_DIM + gc;
          const float mk = mbf ? bf2f(((const unsigned short*)mask)[mIdx])
                               : ((const float*)mask)[mIdx];
          out = e * mk;
          rp[i][r] += e;
        }
        ((unsigned short*)C)[(size_t)grr * ldC + gc] = f2bf(out);
      }
    }
  }
#pragma unroll
  for (int i = 0; i < 4; ++i) {
    const int gr0 = rowBase + wm + i * 16 + quad * 4;
#pragma unroll
    for (int r = 0; r < 4; ++r) {
      float p = rp[i][r];
      p += __shfl_xor(p, 1); p += __shfl_xor(p, 2);
      p += __shfl_xor(p, 4); p += __shfl_xor(p, 8);
      if (l16 == 0) atomicAdd(&rowsum[gr0 + r], p);
    }
  }
}

__global__ __launch_bounds__(256, 4)
void k_gemm_sc(const bf16_t* __restrict__ A, const bf16_t* __restrict__ B,
               void* __restrict__ C, int ldA, int ldB, int ldC, int K,
               float scale, const int* __restrict__ flag,
               const void* __restrict__ mask, float* __restrict__ rowsum) {
  gemm_body<3, 1, 128>(A, B, C, ldA, ldB, ldC, K, scale, flag, mask, rowsum);
}

// ---------------------------------------------------------------------------
// v-part of qkv [S, 6144] (cols 4096..6143) -> vT[D,S], bf16, 32x32 tiles
__global__ void k_transpose(const unsigned short* __restrict__ src, int ldS,
                            unsigned short* __restrict__ dst) {
  __shared__ unsigned short tile[32][33];
  const int bx = blockIdx.x * 32;
  const int by = blockIdx.y * 32;
  const int tx = threadIdx.x & 31, ty = threadIdx.x >> 5;
  for (int r = ty; r < 32; r += 8)
    tile[r][tx] = src[(size_t)(by + r) * ldS + bx + tx];
  __syncthreads();
  for (int r = ty; r < 32; r += 8)
    dst[(size_t)(bx + r) * S_DIM + by + tx] = tile[tx][r];
}

// ---------------------------------------------------------------------------
extern "C" void kernel_launch(void* const* d_in, const int* in_sizes, int n_in,
                              void* d_out, int out_size, void* d_ws, size_t ws_size,
                              hipStream_t stream) {
  const size_t MB = 1024ull * 1024ull;
  char* w = (char*)d_ws;
  int* flag = (int*)w;
  float* rowsum = (float*)(w + 256);                             // 16 KB
  char* base = w + 64 * 1024;
  unsigned short* xb   = (unsigned short*)(base);                // 16 MB
  unsigned short* wqkv = (unsigned short*)(base + 16 * MB);      // 24 MB (Wq|Wk|Wv)
  unsigned short* qkv  = (unsigned short*)(base + 40 * MB);      // 48 MB [S, 6144]
  unsigned short* vT   = (unsigned short*)(base + 88 * MB);      // 16 MB [D, S]
  // attn (32 MB) aliases xb + first 16MB of wqkv (dead after qkv GEMM)
  unsigned short* attn = (unsigned short*)(base);

  k_init<<<16, 256, 0, stream>>>((const unsigned int*)d_in[0], flag, rowsum);

  k_tobf16<<<(S_DIM * D_DIM / 4 + 255) / 256, 256, 0, stream>>>(
      d_in[0], xb, S_DIM * D_DIM / 4, flag);
  k_tobf16w<<<(3 * D_DIM * D_DIM / 4) / 256, 256, 0, stream>>>(
      d_in[1], d_in[2], d_in[3], wqkv, flag);

  // qkv = x @ [Wq;Wk;Wv]^T : [4096, 6144]; 48x16 = 768 blocks = 3 exact
  // rounds of 256 CUs (deep-pipelined 256x128 template)
  k_gemm_qkv8<<<dim3(48, 16), dim3(512), 0, stream>>>(
      (const bf16_t*)xb, (const bf16_t*)wqkv, (void*)qkv, flag);

  // zero the 16 super-diagonal 128-tiles of attn that av@BM=256 reads
  k_zerodiag<<<16, 256, 0, stream>>>(attn);

  // vT[D, S] from v-part of qkv
  k_transpose<<<dim3(D_DIM / 32, S_DIM / 32), 256, 0, stream>>>(
      qkv + 4096, 6144, vT);

  // attn_unnorm = exp(q@k^T/sqrt(d)) * mask, 128x128 triangle tiles (528)
  k_gemm_sc<<<dim3(528), dim3(256), 0, stream>>>(
      (const bf16_t*)qkv, (const bf16_t*)(qkv + 2048), (void*)attn,
      6144, 6144, S_DIM, D_DIM, 0.022097086912079608f /* 1/sqrt(2048) */,
      flag, d_in[4], rowsum);

  // out = (attn_unnorm @ vT^T) / rowsum, 256-row tiles, kEnd=(bm+1)*256,
  // 16x16 = 256 blocks (deep-pipelined template)
  k_gemm_av8<<<dim3(16, 16), dim3(512), 0, stream>>>(
      (const bf16_t*)attn, (const bf16_t*)vT, d_out, flag, rowsum);
}